// Round 9
// baseline (380.930 us; speedup 1.0000x reference)
//
#include <hip/hip_runtime.h>
#include <hip/hip_bf16.h>

typedef __bf16 bf16;
typedef __attribute__((ext_vector_type(8))) __bf16 bf16x8;
typedef __attribute__((ext_vector_type(4))) __bf16 bf16x4;
typedef __attribute__((ext_vector_type(4))) float f32x4;

#define D_MODEL 1024
#define NHEAD 16
#define DK 64
#define BB 4
#define SS 2048
#define MM 8192
#define KK 2048
#define NN 3072

#define LDP 72
#define QSCALE 0.18033688011112042f  // 0.125 * log2(e)

__device__ __forceinline__ void glds16(const bf16* g, bf16* s) {
    __builtin_amdgcn_global_load_lds(
        (const __attribute__((address_space(1))) void*)g,
        (__attribute__((address_space(3))) void*)s, 16, 0, 0);
}

// ---------------------------------------------------------------------------
// pack_all (R8 version, kept): tile-packed XOR-swizzled layout, 4 chunks/thr.
// ---------------------------------------------------------------------------
__device__ __forceinline__ void pack_group4(const float* __restrict__ srow,
                                            bf16* __restrict__ dst,
                                            int mt, int ktile, int mi, int g4) {
    const float4* s4 = (const float4*)&srow[g4 * 32];
    bf16x8 o[4];
#pragma unroll
    for (int q = 0; q < 4; ++q) {
        float4 v0 = s4[2 * q], v1 = s4[2 * q + 1];
        o[q][0]=(bf16)v0.x; o[q][1]=(bf16)v0.y; o[q][2]=(bf16)v0.z; o[q][3]=(bf16)v0.w;
        o[q][4]=(bf16)v1.x; o[q][5]=(bf16)v1.y; o[q][6]=(bf16)v1.z; o[q][7]=(bf16)v1.w;
    }
    const int s = mi & 7;
    const int chi = 4 * (g4 & 1);
    bf16* base = dst + (((((size_t)mt * 32 + ktile) << 10) + mi * 8) << 3);
#pragma unroll
    for (int q = 0; q < 4; ++q)
        *(bf16x8*)&base[((q + chi) ^ s) << 3] = o[q];
}

__global__ void pack_all(const float* __restrict__ Xs, const float* __restrict__ Xt,
                         const float* __restrict__ Wqs, const float* __restrict__ Wqt,
                         const float* __restrict__ Wks, const float* __restrict__ Wkt,
                         const float* __restrict__ Wvs, const float* __restrict__ Wvt,
                         const float* __restrict__ bqs, const float* __restrict__ bqt,
                         const float* __restrict__ bks, const float* __restrict__ bkt,
                         const float* __restrict__ bvs, const float* __restrict__ bvt,
                         bf16* __restrict__ Xp, bf16* __restrict__ Wp,
                         float* __restrict__ biasc) {
    int blk = blockIdx.x;
    if (blk < 2048) {                      // X: 2 tensors * 262,144 groups
        int u = blk * 256 + threadIdx.x;
        int sel = u >> 18;
        int idx4 = u & 262143;
        int m = idx4 >> 5, g4 = idx4 & 31;
        const float* src = sel ? Xt : Xs;
        pack_group4(src + ((size_t)m << 10), Xp,
                    m >> 7, sel * 16 + (g4 >> 1), m & 127, g4);
        return;
    }
    if (blk < 2816) {                      // W: 6 * 32,768 groups
        int v = (blk - 2048) * 256 + threadIdx.x;
        int gi = v >> 15;
        int idx4 = v & 32767;
        int m = idx4 >> 5, g4 = idx4 & 31;
        const float* src = (gi == 0) ? Wqs : (gi == 1) ? Wqt : (gi == 2) ? Wks
                         : (gi == 3) ? Wkt : (gi == 4) ? Wvs : Wvt;
        pack_group4(src + ((size_t)m << 10), Wp,
                    (gi >> 1) * 8 + (m >> 7), (gi & 1) * 16 + (g4 >> 1),
                    m & 127, g4);
        return;
    }
    for (int n = threadIdx.x; n < NN; n += 256) {   // bias tail
        int g = n >> 10, c = n & 1023;
        const float* a = (g == 0) ? bqs : ((g == 1) ? bks : bvs);
        const float* b = (g == 0) ? bqt : ((g == 1) ? bkt : bvt);
        biasc[n] = a[c] + b[c];
    }
}

// ---------------------------------------------------------------------------
// QKV GEMM — R3 (proven best: ~127.5 us).  Unchanged.
// ---------------------------------------------------------------------------
#define VM6 asm volatile("s_waitcnt vmcnt(6)" ::: "memory")
#define VM0 asm volatile("s_waitcnt vmcnt(0)" ::: "memory")
#define VMNONE
#define LGKM0 asm volatile("s_waitcnt lgkmcnt(0)" ::: "memory")

#define STG(gsrc, ldst) do {                                                  \
    glds16((gsrc) + ((size_t)t << 3), (ldst) + (w << 9));                     \
    glds16((gsrc) + (((size_t)t + 512) << 3), (ldst) + ((w + 8) << 9));       \
  } while (0)

#define TILE(P, KT, DO_STAGE, VMOP) do {                                      \
    const bf16* aP = &sA[P][wm << 6];                                         \
    const bf16* bP = &sB[P][bH][bR << 6];                                     \
    bf16x8 aF[4][2], bF[4][2];                                                \
    _Pragma("unroll")                                                         \
    for (int mi = 0; mi < 4; mi++)                                            \
      aF[mi][0] = *(const bf16x8*)&aP[((mi*16+l16)<<6) + ((quad^swz)<<3)];    \
    _Pragma("unroll")                                                         \
    for (int ni = 0; ni < 4; ni++)                                            \
      bF[ni][0] = *(const bf16x8*)&bP[((ni*16+l16)<<6) + ((quad^swz)<<3)];    \
    _Pragma("unroll")                                                         \
    for (int mi = 0; mi < 4; mi++)                                            \
      aF[mi][1] = *(const bf16x8*)&aP[((mi*16+l16)<<6) + (((4+quad)^swz)<<3)];\
    _Pragma("unroll")                                                         \
    for (int ni = 0; ni < 4; ni++)                                            \
      bF[ni][1] = *(const bf16x8*)&bP[((ni*16+l16)<<6) + (((4+quad)^swz)<<3)];\
    __builtin_amdgcn_s_setprio(1);                                            \
    _Pragma("unroll")                                                         \
    for (int mi = 0; mi < 4; mi++)                                            \
      _Pragma("unroll")                                                       \
      for (int ni = 0; ni < 4; ni++)                                          \
        acc[mi][ni] = __builtin_amdgcn_mfma_f32_16x16x32_bf16(                \
            aF[mi][0], bF[ni][0], acc[mi][ni], 0, 0, 0);                      \
    __builtin_amdgcn_s_setprio(0);                                            \
    LGKM0;                                                                    \
    __builtin_amdgcn_sched_barrier(0);                                        \
    __builtin_amdgcn_s_barrier();                                             \
    __builtin_amdgcn_sched_barrier(0);                                        \
    if (DO_STAGE) {                                                           \
      STG(Ag  + ((size_t)((KT) + 2) << 13), &sA[P][0]);                       \
      STG(Bg0 + ((size_t)((KT) + 2) << 13), &sB[P][0][0]);                    \
      STG(Bg1 + ((size_t)((KT) + 2) << 13), &sB[P][1][0]);                    \
    }                                                                         \
    __builtin_amdgcn_s_setprio(1);                                            \
    _Pragma("unroll")                                                         \
    for (int mi = 0; mi < 4; mi++)                                            \
      _Pragma("unroll")                                                       \
      for (int ni = 0; ni < 4; ni++)                                          \
        acc[mi][ni] = __builtin_amdgcn_mfma_f32_16x16x32_bf16(                \
            aF[mi][1], bF[ni][1], acc[mi][ni], 0, 0, 0);                      \
    __builtin_amdgcn_s_setprio(0);                                            \
    VMOP;                                                                     \
    __builtin_amdgcn_s_barrier();                                             \
    __builtin_amdgcn_sched_barrier(0);                                        \
  } while (0)

__global__ __launch_bounds__(512, 2) void gemm_qkv(
    const bf16* __restrict__ Xp, const bf16* __restrict__ Wp,
    const float* __restrict__ biasc,
    bf16* __restrict__ Qb, bf16* __restrict__ Kb, bf16* __restrict__ Vt) {
    __shared__ __align__(16) bf16 sA[2][8192];
    __shared__ __align__(16) bf16 sB[2][2][8192];

    const int t = threadIdx.x, lane = t & 63, w = t >> 6;
    const int quad = lane >> 4, l16 = lane & 15, swz = l16 & 7;
    const int wq = w & 3;
    const int wm = (w >> 2) * 64;
    const int wn = wq * 64;
    const int bH = wq >> 1;
    const int bR = (wq & 1) * 64;

    const int bx = blockIdx.x, by = blockIdx.y;
    const bf16* Ag  = Xp + (((size_t)bx * 32) << 13);
    const bf16* Bg0 = Wp + (((size_t)(by * 2 + 0) * 32) << 13);
    const bf16* Bg1 = Wp + (((size_t)(by * 2 + 1) * 32) << 13);

    f32x4 acc[4][4] = {};

    STG(Ag, &sA[0][0]); STG(Bg0, &sB[0][0][0]); STG(Bg1, &sB[0][1][0]);
    STG(Ag + 8192, &sA[1][0]); STG(Bg0 + 8192, &sB[1][0][0]); STG(Bg1 + 8192, &sB[1][1][0]);
    VM6;
    __builtin_amdgcn_s_barrier();
    __builtin_amdgcn_sched_barrier(0);

    int kt = 0;
#pragma unroll 1
    for (int i = 0; i < 15; i++, kt += 2) {
        TILE(0, kt, 1, VM6);
        TILE(1, kt + 1, 1, VM6);
    }
    TILE(0, 30, 0, VM0);
    TILE(1, 31, 0, VMNONE);

    const int g = by >> 2;
    const int m00 = bx << 7, n00 = by << 8;
#pragma unroll
    for (int mi = 0; mi < 4; mi++) {
        int mbase = m00 + wm + mi * 16 + quad * 4;
#pragma unroll
        for (int ni = 0; ni < 4; ni++) {
            int n = n00 + wn + ni * 16 + l16;
            float bias = biasc[n];
            int c = n & 1023, h = c >> 6, d = c & 63;
#pragma unroll
            for (int r = 0; r < 4; r++) {
                int m = mbase + r;
                int b = m >> 11, s = m & 2047;
                size_t bh = (size_t)(b * NHEAD + h);
                float v = acc[mi][ni][r] + bias;
                if (g == 0)
                    Qb[(bh * SS + s) * DK + d] = (bf16)(v * QSCALE);
                else if (g == 1)
                    Kb[(bh * SS + s) * DK + d] = (bf16)v;
                else
                    Vt[(bh * DK + d) * SS + s] = (bf16)v;
            }
        }
    }
}

// ---------------------------------------------------------------------------
// Flash attention — R9: double-buffered K/V (LDS 50 KB), ONE raw s_barrier
// per key-tile (was 2 __syncthreads, each draining vmcnt), stage(t+1) issued
// right after the barrier so its HBM flight hides under the full compute
// phase (~2000 cyc >> ~900-cyc latency); per-wave vmcnt(0) only at loop top
// where the wait is already satisfied.  Race ledger: stage(t+1) writes
// buf[(t+1)&1], last read at iter t-1, all waves past barrier(t) ✓; reads(t)
// from buf[t&1] disjoint from stage target ✓; sP wave-private (in-wave
// lgkm ordering) ✓.  Compute body unchanged (proven numerics).
// ---------------------------------------------------------------------------
__global__ __launch_bounds__(256) void attn(
    const bf16* __restrict__ Qb, const bf16* __restrict__ Kb,
    const bf16* __restrict__ Vt, float* __restrict__ out) {
    __shared__ __align__(16) bf16 sK[2][64 * 64];
    __shared__ __align__(16) bf16 sV[2][64 * 64];
    __shared__ __align__(16) bf16 sP[4][32 * LDP];

    const int lid = blockIdx.x + gridDim.x * blockIdx.y;   // 0..1023
    const int bh = (lid & 7) * 8 + ((lid >> 3) & 7);       // 0..63
    const int q0 = (lid >> 6) * 128;                       // 0..15 tiles

    const int t = threadIdx.x;
    const int lane = t & 63, w = t >> 6;
    const int quad = lane >> 4, l16 = lane & 15, swz = l16 & 7;
    const int b = bh >> 4, h = bh & 15;

    const bf16* Qp = Qb + ((size_t)bh * SS + q0 + w * 32) * DK;
    bf16x8 qf[2][2];
#pragma unroll
    for (int f = 0; f < 2; f++)
#pragma unroll
        for (int kb = 0; kb < 2; kb++)
            qf[f][kb] = *(const bf16x8*)&Qp[(f * 16 + l16) * DK + kb * 32 + quad * 8];

    f32x4 o[2][4] = {};
    float lsum[2] = {0.f, 0.f};

    const bf16* Kp = Kb + (size_t)bh * SS * DK;
    const bf16* Vp = Vt + (size_t)bh * DK * SS;

    // per-thread staging addresses (linear in key offset kt)
    const int u0 = (w * 2 + 0) * 64 + lane, u1 = u0 + 64;
    const int r0 = u0 >> 3, c0 = (u0 & 7) ^ (r0 & 7);
    const int r1 = u1 >> 3, c1 = (u1 & 7) ^ (r1 & 7);
    const bf16* Kg0 = Kp + r0 * DK + c0 * 8;           // + kt*64
    const bf16* Kg1 = Kp + r1 * DK + c1 * 8;
    const bf16* Vg0 = Vp + (size_t)r0 * SS + c0 * 8;   // + kt
    const bf16* Vg1 = Vp + (size_t)r1 * SS + c1 * 8;
    const int ls0 = (w * 2 + 0) * 512, ls1 = (w * 2 + 1) * 512;

#define ASTG(P, KT) do {                                                      \
    glds16(Kg0 + (size_t)(KT) * 64, &sK[P][ls0]);                             \
    glds16(Kg1 + (size_t)(KT) * 64, &sK[P][ls1]);                             \
    glds16(Vg0 + (KT),              &sV[P][ls0]);                             \
    glds16(Vg1 + (KT),              &sV[P][ls1]);                             \
  } while (0)

    ASTG(0, 0);

#pragma unroll 1
    for (int it = 0; it < 32; ++it) {
        VM0;                               // stage(it) landed (flew under prev compute)
        __builtin_amdgcn_s_barrier();      // all waves: buf[it&1] ready; prev reads done
        __builtin_amdgcn_sched_barrier(0);
        if (it < 31) ASTG((it + 1) & 1, (it + 1) * 64);

        const bf16* kS = &sK[it & 1][0];
        const bf16* vS = &sV[it & 1][0];

        // S^T = K * Q^T
        f32x4 st[2][4] = {};
#pragma unroll
        for (int kb = 0; kb < 2; kb++)
#pragma unroll
            for (int ki = 0; ki < 4; ki++) {
                bf16x8 kf = *(const bf16x8*)&kS[(ki * 16 + l16) * 64 + (((kb * 4 + quad) ^ swz) * 8)];
                st[0][ki] = __builtin_amdgcn_mfma_f32_16x16x32_bf16(kf, qf[0][kb], st[0][ki], 0, 0, 0);
                st[1][ki] = __builtin_amdgcn_mfma_f32_16x16x32_bf16(kf, qf[1][kb], st[1][ki], 0, 0, 0);
            }

        // p = exp2(s); deferred denominator
#pragma unroll
        for (int f = 0; f < 2; f++) {
            float ls = 0.f;
#pragma unroll
            for (int ki = 0; ki < 4; ki++) {
                float p0 = __builtin_amdgcn_exp2f(st[f][ki][0]);
                float p1 = __builtin_amdgcn_exp2f(st[f][ki][1]);
                float p2 = __builtin_amdgcn_exp2f(st[f][ki][2]);
                float p3 = __builtin_amdgcn_exp2f(st[f][ki][3]);
                ls += (p0 + p1) + (p2 + p3);
                bf16x4 pk;
                pk[0] = (bf16)p0; pk[1] = (bf16)p1; pk[2] = (bf16)p2; pk[3] = (bf16)p3;
                *(bf16x4*)&sP[w][(f * 16 + l16) * LDP + ki * 16 + quad * 4] = pk;
            }
            lsum[f] += ls;
        }

        // O += P*V  (sP wave-private: in-wave lgkmcnt covers write->read)
#pragma unroll
        for (int kb = 0; kb < 2; kb++) {
            bf16x8 af0 = *(const bf16x8*)&sP[w][(l16) * LDP + kb * 32 + quad * 8];
            bf16x8 af1 = *(const bf16x8*)&sP[w][(16 + l16) * LDP + kb * 32 + quad * 8];
#pragma unroll
            for (int ni = 0; ni < 4; ni++) {
                bf16x8 vf = *(const bf16x8*)&vS[(ni * 16 + l16) * 64 + (((kb * 4 + quad) ^ swz) * 8)];
                o[0][ni] = __builtin_amdgcn_mfma_f32_16x16x32_bf16(af0, vf, o[0][ni], 0, 0, 0);
                o[1][ni] = __builtin_amdgcn_mfma_f32_16x16x32_bf16(af1, vf, o[1][ni], 0, 0, 0);
            }
        }
    }
#undef ASTG

#pragma unroll
    for (int f = 0; f < 2; f++) {
        lsum[f] += __shfl_xor(lsum[f], 16);
        lsum[f] += __shfl_xor(lsum[f], 32);
    }

    float* op = out + ((size_t)(b * SS + q0 + w * 32)) * D_MODEL + h * DK;
#pragma unroll
    for (int f = 0; f < 2; f++)
#pragma unroll
        for (int r = 0; r < 4; r++) {
            float linv = 1.0f / __shfl(lsum[f], quad * 4 + r);
#pragma unroll
            for (int ni = 0; ni < 4; ni++)
                op[(f * 16 + quad * 4 + r) * D_MODEL + ni * 16 + l16] = o[f][ni][r] * linv;
        }
}

extern "C" void kernel_launch(void* const* d_in, const int* in_sizes, int n_in,
                              void* d_out, int out_size, void* d_ws, size_t ws_size,
                              hipStream_t stream) {
    const float* Xs   = (const float*)d_in[0];
    const float* Xt   = (const float*)d_in[1];
    const float* Wqs  = (const float*)d_in[2];
    const float* bqs  = (const float*)d_in[3];
    const float* Wqt  = (const float*)d_in[4];
    const float* bqt  = (const float*)d_in[5];
    const float* Wks  = (const float*)d_in[6];
    const float* bks  = (const float*)d_in[7];
    const float* Wkt  = (const float*)d_in[8];
    const float* bkt  = (const float*)d_in[9];
    const float* Wvs  = (const float*)d_in[10];
    const float* bvs  = (const float*)d_in[11];
    const float* Wvt  = (const float*)d_in[12];
    const float* bvt  = (const float*)d_in[13];
    float* out = (float*)d_out;

    char* ws = (char*)d_ws;
    bf16*  Xp    = (bf16*)(ws);                 // 32 MB packed-swizzled
    bf16*  Wp    = (bf16*)(ws + 33554432);      // 12 MB packed-swizzled
    float* biasc = (float*)(ws + 46137344);     // 12 KB
    bf16*  Qb    = (bf16*)(ws + 46149632);      // 16 MB
    bf16*  Kb    = (bf16*)(ws + 62926848);      // 16 MB
    bf16*  Vt    = (bf16*)(ws + 79704064);      // 16 MB

    pack_all<<<2817, 256, 0, stream>>>(Xs, Xt, Wqs, Wqt, Wks, Wkt, Wvs, Wvt,
                                       bqs, bqt, bks, bkt, bvs, bvt,
                                       Xp, Wp, biasc);

    gemm_qkv<<<dim3(MM / 128, NN / 256), 512, 0, stream>>>(Xp, Wp, biasc, Qb, Kb, Vt);

    attn<<<dim3(SS / 128, BB * NHEAD), 256, 0, stream>>>(Qb, Kb, Vt, out);
}

// Round 10
// 365.350 us; speedup vs baseline: 1.0426x; 1.0426x over previous
//
#include <hip/hip_runtime.h>
#include <hip/hip_bf16.h>

typedef __bf16 bf16;
typedef __attribute__((ext_vector_type(8))) __bf16 bf16x8;
typedef __attribute__((ext_vector_type(4))) __bf16 bf16x4;
typedef __attribute__((ext_vector_type(4))) float f32x4;

#define D_MODEL 1024
#define NHEAD 16
#define DK 64
#define BB 4
#define SS 2048
#define MM 8192
#define KK 2048
#define NN 3072

#define LDP 72
#define QSCALE 0.18033688011112042f  // 0.125 * log2(e)

__device__ __forceinline__ void glds16(const bf16* g, bf16* s) {
    __builtin_amdgcn_global_load_lds(
        (const __attribute__((address_space(1))) void*)g,
        (__attribute__((address_space(3))) void*)s, 16, 0, 0);
}

// ---------------------------------------------------------------------------
// pack_all (R8 version, kept): tile-packed XOR-swizzled layout, 4 chunks/thr.
// ---------------------------------------------------------------------------
__device__ __forceinline__ void pack_group4(const float* __restrict__ srow,
                                            bf16* __restrict__ dst,
                                            int mt, int ktile, int mi, int g4) {
    const float4* s4 = (const float4*)&srow[g4 * 32];
    bf16x8 o[4];
#pragma unroll
    for (int q = 0; q < 4; ++q) {
        float4 v0 = s4[2 * q], v1 = s4[2 * q + 1];
        o[q][0]=(bf16)v0.x; o[q][1]=(bf16)v0.y; o[q][2]=(bf16)v0.z; o[q][3]=(bf16)v0.w;
        o[q][4]=(bf16)v1.x; o[q][5]=(bf16)v1.y; o[q][6]=(bf16)v1.z; o[q][7]=(bf16)v1.w;
    }
    const int s = mi & 7;
    const int chi = 4 * (g4 & 1);
    bf16* base = dst + (((((size_t)mt * 32 + ktile) << 10) + mi * 8) << 3);
#pragma unroll
    for (int q = 0; q < 4; ++q)
        *(bf16x8*)&base[((q + chi) ^ s) << 3] = o[q];
}

__global__ void pack_all(const float* __restrict__ Xs, const float* __restrict__ Xt,
                         const float* __restrict__ Wqs, const float* __restrict__ Wqt,
                         const float* __restrict__ Wks, const float* __restrict__ Wkt,
                         const float* __restrict__ Wvs, const float* __restrict__ Wvt,
                         const float* __restrict__ bqs, const float* __restrict__ bqt,
                         const float* __restrict__ bks, const float* __restrict__ bkt,
                         const float* __restrict__ bvs, const float* __restrict__ bvt,
                         bf16* __restrict__ Xp, bf16* __restrict__ Wp,
                         float* __restrict__ biasc) {
    int blk = blockIdx.x;
    if (blk < 2048) {                      // X: 2 tensors * 262,144 groups
        int u = blk * 256 + threadIdx.x;
        int sel = u >> 18;
        int idx4 = u & 262143;
        int m = idx4 >> 5, g4 = idx4 & 31;
        const float* src = sel ? Xt : Xs;
        pack_group4(src + ((size_t)m << 10), Xp,
                    m >> 7, sel * 16 + (g4 >> 1), m & 127, g4);
        return;
    }
    if (blk < 2816) {                      // W: 6 * 32,768 groups
        int v = (blk - 2048) * 256 + threadIdx.x;
        int gi = v >> 15;
        int idx4 = v & 32767;
        int m = idx4 >> 5, g4 = idx4 & 31;
        const float* src = (gi == 0) ? Wqs : (gi == 1) ? Wqt : (gi == 2) ? Wks
                         : (gi == 3) ? Wkt : (gi == 4) ? Wvs : Wvt;
        pack_group4(src + ((size_t)m << 10), Wp,
                    (gi >> 1) * 8 + (m >> 7), (gi & 1) * 16 + (g4 >> 1),
                    m & 127, g4);
        return;
    }
    for (int n = threadIdx.x; n < NN; n += 256) {   // bias tail
        int g = n >> 10, c = n & 1023;
        const float* a = (g == 0) ? bqs : ((g == 1) ? bks : bvs);
        const float* b = (g == 0) ? bqt : ((g == 1) ? bkt : bvt);
        biasc[n] = a[c] + b[c];
    }
}

// ---------------------------------------------------------------------------
// QKV GEMM — R3 (proven best: ~127.5 us).  Unchanged.
// ---------------------------------------------------------------------------
#define VM6 asm volatile("s_waitcnt vmcnt(6)" ::: "memory")
#define VM0 asm volatile("s_waitcnt vmcnt(0)" ::: "memory")
#define VMNONE
#define LGKM0 asm volatile("s_waitcnt lgkmcnt(0)" ::: "memory")

#define STG(gsrc, ldst) do {                                                  \
    glds16((gsrc) + ((size_t)t << 3), (ldst) + (w << 9));                     \
    glds16((gsrc) + (((size_t)t + 512) << 3), (ldst) + ((w + 8) << 9));       \
  } while (0)

#define TILE(P, KT, DO_STAGE, VMOP) do {                                      \
    const bf16* aP = &sA[P][wm << 6];                                         \
    const bf16* bP = &sB[P][bH][bR << 6];                                     \
    bf16x8 aF[4][2], bF[4][2];                                                \
    _Pragma("unroll")                                                         \
    for (int mi = 0; mi < 4; mi++)                                            \
      aF[mi][0] = *(const bf16x8*)&aP[((mi*16+l16)<<6) + ((quad^swz)<<3)];    \
    _Pragma("unroll")                                                         \
    for (int ni = 0; ni < 4; ni++)                                            \
      bF[ni][0] = *(const bf16x8*)&bP[((ni*16+l16)<<6) + ((quad^swz)<<3)];    \
    _Pragma("unroll")                                                         \
    for (int mi = 0; mi < 4; mi++)                                            \
      aF[mi][1] = *(const bf16x8*)&aP[((mi*16+l16)<<6) + (((4+quad)^swz)<<3)];\
    _Pragma("unroll")                                                         \
    for (int ni = 0; ni < 4; ni++)                                            \
      bF[ni][1] = *(const bf16x8*)&bP[((ni*16+l16)<<6) + (((4+quad)^swz)<<3)];\
    __builtin_amdgcn_s_setprio(1);                                            \
    _Pragma("unroll")                                                         \
    for (int mi = 0; mi < 4; mi++)                                            \
      _Pragma("unroll")                                                       \
      for (int ni = 0; ni < 4; ni++)                                          \
        acc[mi][ni] = __builtin_amdgcn_mfma_f32_16x16x32_bf16(                \
            aF[mi][0], bF[ni][0], acc[mi][ni], 0, 0, 0);                      \
    __builtin_amdgcn_s_setprio(0);                                            \
    LGKM0;                                                                    \
    __builtin_amdgcn_sched_barrier(0);                                        \
    __builtin_amdgcn_s_barrier();                                             \
    __builtin_amdgcn_sched_barrier(0);                                        \
    if (DO_STAGE) {                                                           \
      STG(Ag  + ((size_t)((KT) + 2) << 13), &sA[P][0]);                       \
      STG(Bg0 + ((size_t)((KT) + 2) << 13), &sB[P][0][0]);                    \
      STG(Bg1 + ((size_t)((KT) + 2) << 13), &sB[P][1][0]);                    \
    }                                                                         \
    __builtin_amdgcn_s_setprio(1);                                            \
    _Pragma("unroll")                                                         \
    for (int mi = 0; mi < 4; mi++)                                            \
      _Pragma("unroll")                                                       \
      for (int ni = 0; ni < 4; ni++)                                          \
        acc[mi][ni] = __builtin_amdgcn_mfma_f32_16x16x32_bf16(                \
            aF[mi][1], bF[ni][1], acc[mi][ni], 0, 0, 0);                      \
    __builtin_amdgcn_s_setprio(0);                                            \
    VMOP;                                                                     \
    __builtin_amdgcn_s_barrier();                                             \
    __builtin_amdgcn_sched_barrier(0);                                        \
  } while (0)

__global__ __launch_bounds__(512, 2) void gemm_qkv(
    const bf16* __restrict__ Xp, const bf16* __restrict__ Wp,
    const float* __restrict__ biasc,
    bf16* __restrict__ Qb, bf16* __restrict__ Kb, bf16* __restrict__ Vt) {
    __shared__ __align__(16) bf16 sA[2][8192];
    __shared__ __align__(16) bf16 sB[2][2][8192];

    const int t = threadIdx.x, lane = t & 63, w = t >> 6;
    const int quad = lane >> 4, l16 = lane & 15, swz = l16 & 7;
    const int wq = w & 3;
    const int wm = (w >> 2) * 64;
    const int wn = wq * 64;
    const int bH = wq >> 1;
    const int bR = (wq & 1) * 64;

    const int bx = blockIdx.x, by = blockIdx.y;
    const bf16* Ag  = Xp + (((size_t)bx * 32) << 13);
    const bf16* Bg0 = Wp + (((size_t)(by * 2 + 0) * 32) << 13);
    const bf16* Bg1 = Wp + (((size_t)(by * 2 + 1) * 32) << 13);

    f32x4 acc[4][4] = {};

    STG(Ag, &sA[0][0]); STG(Bg0, &sB[0][0][0]); STG(Bg1, &sB[0][1][0]);
    STG(Ag + 8192, &sA[1][0]); STG(Bg0 + 8192, &sB[1][0][0]); STG(Bg1 + 8192, &sB[1][1][0]);
    VM6;
    __builtin_amdgcn_s_barrier();
    __builtin_amdgcn_sched_barrier(0);

    int kt = 0;
#pragma unroll 1
    for (int i = 0; i < 15; i++, kt += 2) {
        TILE(0, kt, 1, VM6);
        TILE(1, kt + 1, 1, VM6);
    }
    TILE(0, 30, 0, VM0);
    TILE(1, 31, 0, VMNONE);

    const int g = by >> 2;
    const int m00 = bx << 7, n00 = by << 8;
#pragma unroll
    for (int mi = 0; mi < 4; mi++) {
        int mbase = m00 + wm + mi * 16 + quad * 4;
#pragma unroll
        for (int ni = 0; ni < 4; ni++) {
            int n = n00 + wn + ni * 16 + l16;
            float bias = biasc[n];
            int c = n & 1023, h = c >> 6, d = c & 63;
#pragma unroll
            for (int r = 0; r < 4; r++) {
                int m = mbase + r;
                int b = m >> 11, s = m & 2047;
                size_t bh = (size_t)(b * NHEAD + h);
                float v = acc[mi][ni][r] + bias;
                if (g == 0)
                    Qb[(bh * SS + s) * DK + d] = (bf16)(v * QSCALE);
                else if (g == 1)
                    Kb[(bh * SS + s) * DK + d] = (bf16)v;
                else
                    Vt[(bh * DK + d) * SS + s] = (bf16)v;
            }
        }
    }
}

// ---------------------------------------------------------------------------
// Flash attention — R10: 8 waves / 256 q-rows per block (each wave keeps the
// proven 32-row slice), double-buffered K/V, ONE s_barrier per key-tile.
// Fixes R9's occupancy regression: LDS = 32(K/V dbuf) + 36(sP) = 68 KB ->
// exactly 2 blocks/CU at __launch_bounds__(512,4); grid (2048/256)*64 = 512
// blocks = 2.0 exact rounds.  K/V staging per iteration (16 KB) now serves
// 2x the q-rows -> staging overhead per output halved (2 glds16/thread).
// Ledger (as R9): stage(t+1)->buf[(t+1)&1] whose last readers finished at
// t-1 and all waves passed barrier(t) ✓; vmcnt(0) at loop top retires loads
// that flew under compute(t-1) ✓; sP wave-private (in-wave lgkm order) ✓.
// ---------------------------------------------------------------------------
__global__ __launch_bounds__(512, 4) void attn(
    const bf16* __restrict__ Qb, const bf16* __restrict__ Kb,
    const bf16* __restrict__ Vt, float* __restrict__ out) {
    __shared__ __align__(16) bf16 sK[2][64 * 64];
    __shared__ __align__(16) bf16 sV[2][64 * 64];
    __shared__ __align__(16) bf16 sP[8][32 * LDP];

    const int lid = blockIdx.x + gridDim.x * blockIdx.y;   // 0..511
    const int bh = (lid & 7) * 8 + ((lid >> 3) & 7);       // 0..63 (XCD-aware)
    const int q0 = (lid >> 6) * 256;                       // 8 q-tiles of 256

    const int t = threadIdx.x;
    const int lane = t & 63, w = t >> 6;                   // w = 0..7
    const int quad = lane >> 4, l16 = lane & 15, swz = l16 & 7;
    const int b = bh >> 4, h = bh & 15;

    const bf16* Qp = Qb + ((size_t)bh * SS + q0 + w * 32) * DK;
    bf16x8 qf[2][2];
#pragma unroll
    for (int f = 0; f < 2; f++)
#pragma unroll
        for (int kb = 0; kb < 2; kb++)
            qf[f][kb] = *(const bf16x8*)&Qp[(f * 16 + l16) * DK + kb * 32 + quad * 8];

    f32x4 o[2][4] = {};
    float lsum[2] = {0.f, 0.f};

    const bf16* Kp = Kb + (size_t)bh * SS * DK;
    const bf16* Vp = Vt + (size_t)bh * DK * SS;

    // per-thread staging address (1 K chunk + 1 V chunk per iteration)
    const int row = t >> 3, cc = (t & 7) ^ ((t >> 3) & 7);
    const bf16* Kg = Kp + row * DK + cc * 8;           // + kt*64
    const bf16* Vg = Vp + (size_t)row * SS + cc * 8;   // + kt

#define ASTG(P, KT) do {                                                      \
    glds16(Kg + (size_t)(KT) * 64, &sK[P][t << 3]);                           \
    glds16(Vg + (KT),              &sV[P][t << 3]);                           \
  } while (0)

    ASTG(0, 0);

#pragma unroll 1
    for (int it = 0; it < 32; ++it) {
        VM0;                               // stage(it) landed (flew under prev compute)
        __builtin_amdgcn_s_barrier();      // all waves: buf[it&1] ready; prev reads done
        __builtin_amdgcn_sched_barrier(0);
        if (it < 31) ASTG((it + 1) & 1, (it + 1) * 64);

        const bf16* kS = &sK[it & 1][0];
        const bf16* vS = &sV[it & 1][0];

        // S^T = K * Q^T
        f32x4 st[2][4] = {};
#pragma unroll
        for (int kb = 0; kb < 2; kb++)
#pragma unroll
            for (int ki = 0; ki < 4; ki++) {
                bf16x8 kf = *(const bf16x8*)&kS[(ki * 16 + l16) * 64 + (((kb * 4 + quad) ^ swz) * 8)];
                st[0][ki] = __builtin_amdgcn_mfma_f32_16x16x32_bf16(kf, qf[0][kb], st[0][ki], 0, 0, 0);
                st[1][ki] = __builtin_amdgcn_mfma_f32_16x16x32_bf16(kf, qf[1][kb], st[1][ki], 0, 0, 0);
            }

        // p = exp2(s); deferred denominator
#pragma unroll
        for (int f = 0; f < 2; f++) {
            float ls = 0.f;
#pragma unroll
            for (int ki = 0; ki < 4; ki++) {
                float p0 = __builtin_amdgcn_exp2f(st[f][ki][0]);
                float p1 = __builtin_amdgcn_exp2f(st[f][ki][1]);
                float p2 = __builtin_amdgcn_exp2f(st[f][ki][2]);
                float p3 = __builtin_amdgcn_exp2f(st[f][ki][3]);
                ls += (p0 + p1) + (p2 + p3);
                bf16x4 pk;
                pk[0] = (bf16)p0; pk[1] = (bf16)p1; pk[2] = (bf16)p2; pk[3] = (bf16)p3;
                *(bf16x4*)&sP[w][(f * 16 + l16) * LDP + ki * 16 + quad * 4] = pk;
            }
            lsum[f] += ls;
        }

        // O += P*V  (sP wave-private: in-wave lgkmcnt covers write->read)
#pragma unroll
        for (int kb = 0; kb < 2; kb++) {
            bf16x8 af0 = *(const bf16x8*)&sP[w][(l16) * LDP + kb * 32 + quad * 8];
            bf16x8 af1 = *(const bf16x8*)&sP[w][(16 + l16) * LDP + kb * 32 + quad * 8];
#pragma unroll
            for (int ni = 0; ni < 4; ni++) {
                bf16x8 vf = *(const bf16x8*)&vS[(ni * 16 + l16) * 64 + (((kb * 4 + quad) ^ swz) * 8)];
                o[0][ni] = __builtin_amdgcn_mfma_f32_16x16x32_bf16(af0, vf, o[0][ni], 0, 0, 0);
                o[1][ni] = __builtin_amdgcn_mfma_f32_16x16x32_bf16(af1, vf, o[1][ni], 0, 0, 0);
            }
        }
    }
#undef ASTG

#pragma unroll
    for (int f = 0; f < 2; f++) {
        lsum[f] += __shfl_xor(lsum[f], 16);
        lsum[f] += __shfl_xor(lsum[f], 32);
    }

    float* op = out + ((size_t)(b * SS + q0 + w * 32)) * D_MODEL + h * DK;
#pragma unroll
    for (int f = 0; f < 2; f++)
#pragma unroll
        for (int r = 0; r < 4; r++) {
            float linv = 1.0f / __shfl(lsum[f], quad * 4 + r);
#pragma unroll
            for (int ni = 0; ni < 4; ni++)
                op[(f * 16 + quad * 4 + r) * D_MODEL + ni * 16 + l16] = o[f][ni][r] * linv;
        }
}

extern "C" void kernel_launch(void* const* d_in, const int* in_sizes, int n_in,
                              void* d_out, int out_size, void* d_ws, size_t ws_size,
                              hipStream_t stream) {
    const float* Xs   = (const float*)d_in[0];
    const float* Xt   = (const float*)d_in[1];
    const float* Wqs  = (const float*)d_in[2];
    const float* bqs  = (const float*)d_in[3];
    const float* Wqt  = (const float*)d_in[4];
    const float* bqt  = (const float*)d_in[5];
    const float* Wks  = (const float*)d_in[6];
    const float* bks  = (const float*)d_in[7];
    const float* Wkt  = (const float*)d_in[8];
    const float* bkt  = (const float*)d_in[9];
    const float* Wvs  = (const float*)d_in[10];
    const float* bvs  = (const float*)d_in[11];
    const float* Wvt  = (const float*)d_in[12];
    const float* bvt  = (const float*)d_in[13];
    float* out = (float*)d_out;

    char* ws = (char*)d_ws;
    bf16*  Xp    = (bf16*)(ws);                 // 32 MB packed-swizzled
    bf16*  Wp    = (bf16*)(ws + 33554432);      // 12 MB packed-swizzled
    float* biasc = (float*)(ws + 46137344);     // 12 KB
    bf16*  Qb    = (bf16*)(ws + 46149632);      // 16 MB
    bf16*  Kb    = (bf16*)(ws + 62926848);      // 16 MB
    bf16*  Vt    = (bf16*)(ws + 79704064);      // 16 MB

    pack_all<<<2817, 256, 0, stream>>>(Xs, Xt, Wqs, Wqt, Wks, Wkt, Wvs, Wvt,
                                       bqs, bqt, bks, bkt, bvs, bvt,
                                       Xp, Wp, biasc);

    gemm_qkv<<<dim3(MM / 128, NN / 256), 512, 0, stream>>>(Xp, Wp, biasc, Qb, Kb, Vt);

    attn<<<dim3(SS / 256, BB * NHEAD), 512, 0, stream>>>(Qb, Kb, Vt, out);
}

// Round 11
// 358.742 us; speedup vs baseline: 1.0619x; 1.0184x over previous
//
#include <hip/hip_runtime.h>
#include <hip/hip_bf16.h>

typedef __bf16 bf16;
typedef __attribute__((ext_vector_type(8))) __bf16 bf16x8;
typedef __attribute__((ext_vector_type(4))) __bf16 bf16x4;
typedef __attribute__((ext_vector_type(4))) float f32x4;

#define D_MODEL 1024
#define NHEAD 16
#define DK 64
#define BB 4
#define SS 2048
#define MM 8192
#define KK 2048
#define NN 3072

#define LDP 72
#define QSCALE 0.18033688011112042f  // 0.125 * log2(e)

__device__ __forceinline__ void glds16(const bf16* g, bf16* s) {
    __builtin_amdgcn_global_load_lds(
        (const __attribute__((address_space(1))) void*)g,
        (__attribute__((address_space(3))) void*)s, 16, 0, 0);
}

// ---------------------------------------------------------------------------
// pack_all (R8 version, kept): tile-packed XOR-swizzled layout, 4 chunks/thr.
// ---------------------------------------------------------------------------
__device__ __forceinline__ void pack_group4(const float* __restrict__ srow,
                                            bf16* __restrict__ dst,
                                            int mt, int ktile, int mi, int g4) {
    const float4* s4 = (const float4*)&srow[g4 * 32];
    bf16x8 o[4];
#pragma unroll
    for (int q = 0; q < 4; ++q) {
        float4 v0 = s4[2 * q], v1 = s4[2 * q + 1];
        o[q][0]=(bf16)v0.x; o[q][1]=(bf16)v0.y; o[q][2]=(bf16)v0.z; o[q][3]=(bf16)v0.w;
        o[q][4]=(bf16)v1.x; o[q][5]=(bf16)v1.y; o[q][6]=(bf16)v1.z; o[q][7]=(bf16)v1.w;
    }
    const int s = mi & 7;
    const int chi = 4 * (g4 & 1);
    bf16* base = dst + (((((size_t)mt * 32 + ktile) << 10) + mi * 8) << 3);
#pragma unroll
    for (int q = 0; q < 4; ++q)
        *(bf16x8*)&base[((q + chi) ^ s) << 3] = o[q];
}

__global__ void pack_all(const float* __restrict__ Xs, const float* __restrict__ Xt,
                         const float* __restrict__ Wqs, const float* __restrict__ Wqt,
                         const float* __restrict__ Wks, const float* __restrict__ Wkt,
                         const float* __restrict__ Wvs, const float* __restrict__ Wvt,
                         const float* __restrict__ bqs, const float* __restrict__ bqt,
                         const float* __restrict__ bks, const float* __restrict__ bkt,
                         const float* __restrict__ bvs, const float* __restrict__ bvt,
                         bf16* __restrict__ Xp, bf16* __restrict__ Wp,
                         float* __restrict__ biasc) {
    int blk = blockIdx.x;
    if (blk < 2048) {                      // X: 2 tensors * 262,144 groups
        int u = blk * 256 + threadIdx.x;
        int sel = u >> 18;
        int idx4 = u & 262143;
        int m = idx4 >> 5, g4 = idx4 & 31;
        const float* src = sel ? Xt : Xs;
        pack_group4(src + ((size_t)m << 10), Xp,
                    m >> 7, sel * 16 + (g4 >> 1), m & 127, g4);
        return;
    }
    if (blk < 2816) {                      // W: 6 * 32,768 groups
        int v = (blk - 2048) * 256 + threadIdx.x;
        int gi = v >> 15;
        int idx4 = v & 32767;
        int m = idx4 >> 5, g4 = idx4 & 31;
        const float* src = (gi == 0) ? Wqs : (gi == 1) ? Wqt : (gi == 2) ? Wks
                         : (gi == 3) ? Wkt : (gi == 4) ? Wvs : Wvt;
        pack_group4(src + ((size_t)m << 10), Wp,
                    (gi >> 1) * 8 + (m >> 7), (gi & 1) * 16 + (g4 >> 1),
                    m & 127, g4);
        return;
    }
    for (int n = threadIdx.x; n < NN; n += 256) {   // bias tail
        int g = n >> 10, c = n & 1023;
        const float* a = (g == 0) ? bqs : ((g == 1) ? bks : bvs);
        const float* b = (g == 0) ? bqt : ((g == 1) ? bkt : bvt);
        biasc[n] = a[c] + b[c];
    }
}

// ---------------------------------------------------------------------------
// QKV GEMM — R11: R3's counted-vmcnt 2-barrier schedule at R0's residency.
// 128x128 tile, BK=64, 4 waves (2M x 2N) each 64x64, 64 KiB LDS dbuf ->
// 2 blocks/CU (the cross-block TLP R0 had, which fills R3's barrier-drain
// bubbles).  Grid (64,24) = 1536 blocks = 3.0 exact rounds at 2/CU.
// Per tile: {8 ds_reads + 16 MFMA} kb0; lgkm0+barrier (buf[P] reads retired
// -> safe stage dest); stage t+2 (8 glds16/thread, 32 KB); {kb1 16 MFMA};
// vmcnt(8) retires t+1's 8, leaves t+2's 8 in flight; barrier.  Never
// vmcnt(0) in the main loop.
// ---------------------------------------------------------------------------
#define VM8 asm volatile("s_waitcnt vmcnt(8)" ::: "memory")
#define VM0 asm volatile("s_waitcnt vmcnt(0)" ::: "memory")
#define VMNONE
#define LGKM0 asm volatile("s_waitcnt lgkmcnt(0)" ::: "memory")

// stage A-tile (16 KB) + B-tile (16 KB) for K-tile KT: 8 glds16/thread (256t)
#define STG(KT, sAd, sBd) do {                                                \
    size_t o = (((size_t)(KT)) << 13) + ((size_t)t << 3);                     \
    glds16(Ag + o,         (sAd) + (w << 9));                                 \
    glds16(Ag + o + 2048,  (sAd) + ((w + 4) << 9));                          \
    glds16(Ag + o + 4096,  (sAd) + ((w + 8) << 9));                          \
    glds16(Ag + o + 6144,  (sAd) + ((w + 12) << 9));                         \
    glds16(Bg + o,         (sBd) + (w << 9));                                 \
    glds16(Bg + o + 2048,  (sBd) + ((w + 4) << 9));                          \
    glds16(Bg + o + 4096,  (sBd) + ((w + 8) << 9));                          \
    glds16(Bg + o + 6144,  (sBd) + ((w + 12) << 9));                         \
  } while (0)

#define TILE(P, KT, DO_STAGE, VMOP) do {                                      \
    const bf16* aP = &sA[P][wm << 6];                                         \
    const bf16* bP = &sB[P][wn << 6];                                         \
    bf16x8 aF[4][2], bF[4][2];                                                \
    _Pragma("unroll")                                                         \
    for (int mi = 0; mi < 4; mi++)                                            \
      aF[mi][0] = *(const bf16x8*)&aP[((mi*16+l16)<<6) + ((quad^swz)<<3)];    \
    _Pragma("unroll")                                                         \
    for (int ni = 0; ni < 4; ni++)                                            \
      bF[ni][0] = *(const bf16x8*)&bP[((ni*16+l16)<<6) + ((quad^swz)<<3)];    \
    _Pragma("unroll")                                                         \
    for (int mi = 0; mi < 4; mi++)                                            \
      aF[mi][1] = *(const bf16x8*)&aP[((mi*16+l16)<<6) + (((4+quad)^swz)<<3)];\
    _Pragma("unroll")                                                         \
    for (int ni = 0; ni < 4; ni++)                                            \
      bF[ni][1] = *(const bf16x8*)&bP[((ni*16+l16)<<6) + (((4+quad)^swz)<<3)];\
    __builtin_amdgcn_s_setprio(1);                                            \
    _Pragma("unroll")                                                         \
    for (int mi = 0; mi < 4; mi++)                                            \
      _Pragma("unroll")                                                       \
      for (int ni = 0; ni < 4; ni++)                                          \
        acc[mi][ni] = __builtin_amdgcn_mfma_f32_16x16x32_bf16(                \
            aF[mi][0], bF[ni][0], acc[mi][ni], 0, 0, 0);                      \
    __builtin_amdgcn_s_setprio(0);                                            \
    LGKM0;                                                                    \
    __builtin_amdgcn_sched_barrier(0);                                        \
    __builtin_amdgcn_s_barrier();                                             \
    __builtin_amdgcn_sched_barrier(0);                                        \
    if (DO_STAGE) STG((KT) + 2, &sA[P][0], &sB[P][0]);                        \
    __builtin_amdgcn_s_setprio(1);                                            \
    _Pragma("unroll")                                                         \
    for (int mi = 0; mi < 4; mi++)                                            \
      _Pragma("unroll")                                                       \
      for (int ni = 0; ni < 4; ni++)                                          \
        acc[mi][ni] = __builtin_amdgcn_mfma_f32_16x16x32_bf16(                \
            aF[mi][1], bF[ni][1], acc[mi][ni], 0, 0, 0);                      \
    __builtin_amdgcn_s_setprio(0);                                            \
    VMOP;                                                                     \
    __builtin_amdgcn_s_barrier();                                             \
    __builtin_amdgcn_sched_barrier(0);                                        \
  } while (0)

__global__ __launch_bounds__(256, 2) void gemm_qkv(
    const bf16* __restrict__ Xp, const bf16* __restrict__ Wp,
    const float* __restrict__ biasc,
    bf16* __restrict__ Qb, bf16* __restrict__ Kb, bf16* __restrict__ Vt) {
    // per buf: A packed 128x64 tile (16 KB) + B packed tile (16 KB) = 64 KiB
    __shared__ __align__(16) bf16 sA[2][8192];
    __shared__ __align__(16) bf16 sB[2][8192];

    const int t = threadIdx.x, lane = t & 63, w = t >> 6;   // w = 0..3
    const int quad = lane >> 4, l16 = lane & 15, swz = l16 & 7;
    const int wm = (w >> 1) * 64;    // wave M offset in 128-tile
    const int wn = (w & 1) * 64;     // wave N offset in 128-tile

    const int bx = blockIdx.x, by = blockIdx.y;
    const bf16* Ag = Xp + (((size_t)bx * 32) << 13);
    const bf16* Bg = Wp + (((size_t)by * 32) << 13);

    f32x4 acc[4][4] = {};

    // prologue: stage tiles 0 (buf0) and 1 (buf1); wait for tile 0 only
    STG(0, &sA[0][0], &sB[0][0]);
    STG(1, &sA[1][0], &sB[1][0]);
    VM8;
    __builtin_amdgcn_s_barrier();
    __builtin_amdgcn_sched_barrier(0);

    int kt = 0;
#pragma unroll 1
    for (int i = 0; i < 15; i++, kt += 2) {   // tiles 0..29, staging 2..31
        TILE(0, kt, 1, VM8);
        TILE(1, kt + 1, 1, VM8);
    }
    TILE(0, 30, 0, VM0);      // drain: only tile 31's loads remain
    TILE(1, 31, 0, VMNONE);

    // epilogue (proven routing; BM=128, BN=128; g per-n)
    const int m00 = bx << 7, n00 = by << 7;
#pragma unroll
    for (int mi = 0; mi < 4; mi++) {
        int mbase = m00 + wm + mi * 16 + quad * 4;
#pragma unroll
        for (int ni = 0; ni < 4; ni++) {
            int n = n00 + wn + ni * 16 + l16;
            float bias = biasc[n];
            int g = n >> 10;
            int c = n & 1023, h = c >> 6, d = c & 63;
#pragma unroll
            for (int r = 0; r < 4; r++) {
                int m = mbase + r;
                int b = m >> 11, s = m & 2047;
                size_t bh = (size_t)(b * NHEAD + h);
                float v = acc[mi][ni][r] + bias;
                if (g == 0)
                    Qb[(bh * SS + s) * DK + d] = (bf16)(v * QSCALE);
                else if (g == 1)
                    Kb[(bh * SS + s) * DK + d] = (bf16)v;
                else
                    Vt[(bh * DK + d) * SS + s] = (bf16)v;
            }
        }
    }
}

// ---------------------------------------------------------------------------
// Flash attention — R10 (proven best): 8 waves / 256 q-rows, dbuf K/V,
// one s_barrier per key-tile, 68 KB LDS -> exactly 2 blocks/CU, 512 blocks
// = 2.0 exact rounds.  Unchanged.
// ---------------------------------------------------------------------------
__global__ __launch_bounds__(512, 4) void attn(
    const bf16* __restrict__ Qb, const bf16* __restrict__ Kb,
    const bf16* __restrict__ Vt, float* __restrict__ out) {
    __shared__ __align__(16) bf16 sK[2][64 * 64];
    __shared__ __align__(16) bf16 sV[2][64 * 64];
    __shared__ __align__(16) bf16 sP[8][32 * LDP];

    const int lid = blockIdx.x + gridDim.x * blockIdx.y;   // 0..511
    const int bh = (lid & 7) * 8 + ((lid >> 3) & 7);       // 0..63 (XCD-aware)
    const int q0 = (lid >> 6) * 256;                       // 8 q-tiles of 256

    const int t = threadIdx.x;
    const int lane = t & 63, w = t >> 6;                   // w = 0..7
    const int quad = lane >> 4, l16 = lane & 15, swz = l16 & 7;
    const int b = bh >> 4, h = bh & 15;

    const bf16* Qp = Qb + ((size_t)bh * SS + q0 + w * 32) * DK;
    bf16x8 qf[2][2];
#pragma unroll
    for (int f = 0; f < 2; f++)
#pragma unroll
        for (int kb = 0; kb < 2; kb++)
            qf[f][kb] = *(const bf16x8*)&Qp[(f * 16 + l16) * DK + kb * 32 + quad * 8];

    f32x4 o[2][4] = {};
    float lsum[2] = {0.f, 0.f};

    const bf16* Kp = Kb + (size_t)bh * SS * DK;
    const bf16* Vp = Vt + (size_t)bh * DK * SS;

    const int row = t >> 3, cc = (t & 7) ^ ((t >> 3) & 7);
    const bf16* Kg = Kp + row * DK + cc * 8;           // + kt*64
    const bf16* Vg = Vp + (size_t)row * SS + cc * 8;   // + kt

#define ASTG(P, KT) do {                                                      \
    glds16(Kg + (size_t)(KT) * 64, &sK[P][t << 3]);                           \
    glds16(Vg + (KT),              &sV[P][t << 3]);                           \
  } while (0)

    ASTG(0, 0);

#pragma unroll 1
    for (int it = 0; it < 32; ++it) {
        VM0;                               // stage(it) landed (flew under prev compute)
        __builtin_amdgcn_s_barrier();      // all waves: buf[it&1] ready; prev reads done
        __builtin_amdgcn_sched_barrier(0);
        if (it < 31) ASTG((it + 1) & 1, (it + 1) * 64);

        const bf16* kS = &sK[it & 1][0];
        const bf16* vS = &sV[it & 1][0];

        // S^T = K * Q^T
        f32x4 st[2][4] = {};
#pragma unroll
        for (int kb = 0; kb < 2; kb++)
#pragma unroll
            for (int ki = 0; ki < 4; ki++) {
                bf16x8 kf = *(const bf16x8*)&kS[(ki * 16 + l16) * 64 + (((kb * 4 + quad) ^ swz) * 8)];
                st[0][ki] = __builtin_amdgcn_mfma_f32_16x16x32_bf16(kf, qf[0][kb], st[0][ki], 0, 0, 0);
                st[1][ki] = __builtin_amdgcn_mfma_f32_16x16x32_bf16(kf, qf[1][kb], st[1][ki], 0, 0, 0);
            }

        // p = exp2(s); deferred denominator
#pragma unroll
        for (int f = 0; f < 2; f++) {
            float ls = 0.f;
#pragma unroll
            for (int ki = 0; ki < 4; ki++) {
                float p0 = __builtin_amdgcn_exp2f(st[f][ki][0]);
                float p1 = __builtin_amdgcn_exp2f(st[f][ki][1]);
                float p2 = __builtin_amdgcn_exp2f(st[f][ki][2]);
                float p3 = __builtin_amdgcn_exp2f(st[f][ki][3]);
                ls += (p0 + p1) + (p2 + p3);
                bf16x4 pk;
                pk[0] = (bf16)p0; pk[1] = (bf16)p1; pk[2] = (bf16)p2; pk[3] = (bf16)p3;
                *(bf16x4*)&sP[w][(f * 16 + l16) * LDP + ki * 16 + quad * 4] = pk;
            }
            lsum[f] += ls;
        }

        // O += P*V  (sP wave-private: in-wave lgkmcnt covers write->read)
#pragma unroll
        for (int kb = 0; kb < 2; kb++) {
            bf16x8 af0 = *(const bf16x8*)&sP[w][(l16) * LDP + kb * 32 + quad * 8];
            bf16x8 af1 = *(const bf16x8*)&sP[w][(16 + l16) * LDP + kb * 32 + quad * 8];
#pragma unroll
            for (int ni = 0; ni < 4; ni++) {
                bf16x8 vf = *(const bf16x8*)&vS[(ni * 16 + l16) * 64 + (((kb * 4 + quad) ^ swz) * 8)];
                o[0][ni] = __builtin_amdgcn_mfma_f32_16x16x32_bf16(af0, vf, o[0][ni], 0, 0, 0);
                o[1][ni] = __builtin_amdgcn_mfma_f32_16x16x32_bf16(af1, vf, o[1][ni], 0, 0, 0);
            }
        }
    }
#undef ASTG

#pragma unroll
    for (int f = 0; f < 2; f++) {
        lsum[f] += __shfl_xor(lsum[f], 16);
        lsum[f] += __shfl_xor(lsum[f], 32);
    }

    float* op = out + ((size_t)(b * SS + q0 + w * 32)) * D_MODEL + h * DK;
#pragma unroll
    for (int f = 0; f < 2; f++)
#pragma unroll
        for (int r = 0; r < 4; r++) {
            float linv = 1.0f / __shfl(lsum[f], quad * 4 + r);
#pragma unroll
            for (int ni = 0; ni < 4; ni++)
                op[(f * 16 + quad * 4 + r) * D_MODEL + ni * 16 + l16] = o[f][ni][r] * linv;
        }
}

extern "C" void kernel_launch(void* const* d_in, const int* in_sizes, int n_in,
                              void* d_out, int out_size, void* d_ws, size_t ws_size,
                              hipStream_t stream) {
    const float* Xs   = (const float*)d_in[0];
    const float* Xt   = (const float*)d_in[1];
    const float* Wqs  = (const float*)d_in[2];
    const float* bqs  = (const float*)d_in[3];
    const float* Wqt  = (const float*)d_in[4];
    const float* bqt  = (const float*)d_in[5];
    const float* Wks  = (const float*)d_in[6];
    const float* bks  = (const float*)d_in[7];
    const float* Wkt  = (const float*)d_in[8];
    const float* bkt  = (const float*)d_in[9];
    const float* Wvs  = (const float*)d_in[10];
    const float* bvs  = (const float*)d_in[11];
    const float* Wvt  = (const float*)d_in[12];
    const float* bvt  = (const float*)d_in[13];
    float* out = (float*)d_out;

    char* ws = (char*)d_ws;
    bf16*  Xp    = (bf16*)(ws);                 // 32 MB packed-swizzled
    bf16*  Wp    = (bf16*)(ws + 33554432);      // 12 MB packed-swizzled
    float* biasc = (float*)(ws + 46137344);     // 12 KB
    bf16*  Qb    = (bf16*)(ws + 46149632);      // 16 MB
    bf16*  Kb    = (bf16*)(ws + 62926848);      // 16 MB
    bf16*  Vt    = (bf16*)(ws + 79704064);      // 16 MB

    pack_all<<<2817, 256, 0, stream>>>(Xs, Xt, Wqs, Wqt, Wks, Wkt, Wvs, Wvt,
                                       bqs, bqt, bks, bkt, bvs, bvt,
                                       Xp, Wp, biasc);

    gemm_qkv<<<dim3(MM / 128, NN / 128), 256, 0, stream>>>(Xp, Wp, biasc, Qb, Kb, Vt);

    attn<<<dim3(SS / 256, BB * NHEAD), 512, 0, stream>>>(Qb, Kb, Vt, out);
}